// Round 2
// baseline (367.620 us; speedup 1.0000x reference)
//
#include <hip/hip_runtime.h>
#include <hip/hip_bf16.h>
#include <cmath>

typedef unsigned short u16;
typedef __attribute__((ext_vector_type(8))) short bf16x8;
typedef __attribute__((ext_vector_type(4))) float f32x4;
typedef __attribute__((ext_vector_type(4))) unsigned short u16x4;

// Problem constants: B=8, C=128, H=128, WIN=4, K=3, WS=64, L=16384
// Workspace layout (bytes):
#define OFF_AGG   0u          // 5 stats * 8b * 4w * 128c f32 = 81920
#define OFF_WW    81920u      // 32 f32
#define OFF_R     82048u      // 4*128*9 f32 = 18432
#define OFF_FSUM  100480u     // 128 f32
#define OFF_GKT   100992u     // 4*128*128 f32 = 262144
#define OFF_A     363136u     // 4*128*1152 f32 = 2359296
#define OFF_P     2722432u    // 2359296
#define OFF_M     5081728u    // [w][t][o][c] f32 = 2359296
#define OFF_KEFF  7441024u    // [b][t][o][c] u16 = 2359296
#define OFF_XPAD  9800320u    // [b][130][130][128] u16 = 34611200  (total ~42.4 MB)

__device__ __forceinline__ u16 f2bf(float f) {
  union { float f; unsigned int u; } v; v.f = f;
  unsigned int r = v.u + 0x7FFFu + ((v.u >> 16) & 1u);
  return (u16)(r >> 16);
}

// K1: fp32 x -> padded bf16 image [b][130][130][128]; window boundary aggregates via atomics.
// agg stats: 0=T 1=rowFirst 2=rowLast 3=colFirst 4=colLast, layout [stat][b][w][c]
__global__ void k1_pad_agg(const float* __restrict__ x, u16* __restrict__ xpad,
                           float* __restrict__ agg) {
  const int c = threadIdx.x;      // 0..127
  const int rp = blockIdx.x;      // padded row 0..129
  const int b = blockIdx.y;
  const size_t xpb = ((size_t)b * 130 + rp) * 130 * 128;
  if (rp == 0 || rp == 129) {
    for (int q = 0; q < 130; ++q) xpad[xpb + (size_t)q * 128 + c] = 0;
    return;
  }
  const int r = rp - 1;
  xpad[xpb + c] = 0;
  xpad[xpb + (size_t)129 * 128 + c] = 0;
  const float* xr = x + ((size_t)b * 16384 + (size_t)r * 128) * 128 + c;
  float t0 = 0.f, t1 = 0.f, cF0 = 0.f, cL0 = 0.f, cF1 = 0.f, cL1 = 0.f;
  #pragma unroll 4
  for (int q = 0; q < 128; ++q) {
    float v = xr[(size_t)q * 128];
    xpad[xpb + (size_t)(q + 1) * 128 + c] = f2bf(v);
    if (q < 64) t0 += v; else t1 += v;
    if (q == 0) cF0 = v;
    if (q == 63) cL0 = v;
    if (q == 64) cF1 = v;
    if (q == 127) cL1 = v;
  }
  const int i = r >> 6, rw = r & 63;
  const int a0 = b * 512 + (i * 2) * 128 + c;
  const int a1 = b * 512 + (i * 2 + 1) * 128 + c;
  atomicAdd(&agg[a0], t0);
  atomicAdd(&agg[a1], t1);
  atomicAdd(&agg[3 * 4096 + a0], cF0);
  atomicAdd(&agg[3 * 4096 + a1], cF1);
  atomicAdd(&agg[4 * 4096 + a0], cL0);
  atomicAdd(&agg[4 * 4096 + a1], cL1);
  if (rw == 0)  { atomicAdd(&agg[4096 + a0], t0); atomicAdd(&agg[4096 + a1], t1); }
  if (rw == 63) { atomicAdd(&agg[2 * 4096 + a0], t0); atomicAdd(&agg[2 * 4096 + a1], t1); }
}

// R[w,c,t] = sum_o dc_w[w,o] * conv1_w[w*128+o, c, t]    (4608 outputs, K=128)
__global__ void kR(const float* __restrict__ dc_w, const float* __restrict__ conv1_w,
                   float* __restrict__ R) {
  int gid = blockIdx.x * 256 + threadIdx.x;   // 0..4607
  int w = gid / 1152, m = gid % 1152;
  float s = 0.f;
  for (int o = 0; o < 128; ++o)
    s += dc_w[w * 128 + o] * conv1_w[(size_t)(w * 128 + o) * 1152 + m];
  R[gid] = s;
}

// gkT[w][j][c] = gk_w[c][w][j]
__global__ void kT(const float* __restrict__ gk_w, float* __restrict__ gkT) {
  int gid = blockIdx.x * 256 + threadIdx.x;   // 0..65535
  int w = gid >> 14, j = (gid >> 7) & 127, c = gid & 127;
  gkT[gid] = gk_w[c * 512 + w * 128 + j];
}

// fsum[o] = sum_oc fusion_w[o, 512+oc]
__global__ void kF(const float* __restrict__ fusion_w, float* __restrict__ fsum) {
  int o = threadIdx.x;
  float s = 0.f;
  for (int oc = 0; oc < 128; ++oc) s += fusion_w[o * 640 + 512 + oc];
  fsum[o] = s;
}

// K2: per-batch SE gate ww[b][w] from aggregates (S trick) + exact-gelu MLP + sigmoid
__global__ void k2_ww(const float* __restrict__ x, const float* __restrict__ agg,
                      const float* __restrict__ R, const float* __restrict__ dc_b,
                      const float* __restrict__ l1_w, const float* __restrict__ l1_b,
                      const float* __restrict__ l2_w, const float* __restrict__ l2_b,
                      float* __restrict__ ww) {
  const int b = blockIdx.x;
  const int tid = threadIdx.x;
  const int w = tid >> 6, lane = tid & 63;
  __shared__ float red[4];
  float partial = 0.f;
  const int i = w >> 1, j = w & 1;
  const int r0 = i * 64, s0 = j * 64;
  const size_t base = (size_t)b * 16384 * 128;
  #pragma unroll
  for (int k = 0; k < 2; ++k) {
    const int c = lane * 2 + k;
    const int ai = b * 512 + w * 128 + c;
    float T  = agg[ai];
    float rF = agg[4096 + ai];
    float rL = agg[2 * 4096 + ai];
    float cF = agg[3 * 4096 + ai];
    float cL = agg[4 * 4096 + ai];
    float c00 = x[base + ((size_t)(r0 + 0)  * 128 + (s0 + 0))  * 128 + c];
    float c0L = x[base + ((size_t)(r0 + 0)  * 128 + (s0 + 63)) * 128 + c];
    float cL0 = x[base + ((size_t)(r0 + 63) * 128 + (s0 + 0))  * 128 + c];
    float cLL = x[base + ((size_t)(r0 + 63) * 128 + (s0 + 63)) * 128 + c];
    float S[9];
    S[0] = T - rL - cL + cLL;
    S[1] = T - rL;
    S[2] = T - rL - cF + cL0;
    S[3] = T - cL;
    S[4] = T;
    S[5] = T - cF;
    S[6] = T - rF - cL + c0L;
    S[7] = T - rF;
    S[8] = T - rF - cF + c00;
    const float* Rp = R + (w * 128 + c) * 9;
    #pragma unroll
    for (int t = 0; t < 9; ++t) partial += S[t] * Rp[t];
  }
  for (int off = 32; off > 0; off >>= 1) partial += __shfl_xor(partial, off, 64);
  if (lane == 0) red[w] = partial;
  __syncthreads();
  if (tid == 0) {
    float ww0[4];
    #pragma unroll
    for (int w2 = 0; w2 < 4; ++w2) ww0[w2] = red[w2] * (1.f / 4096.f) + dc_b[w2];
    float h1[16];
    for (int i2 = 0; i2 < 16; ++i2) {
      float s = l1_b[i2];
      #pragma unroll
      for (int w2 = 0; w2 < 4; ++w2) s += l1_w[i2 * 4 + w2] * ww0[w2];
      h1[i2] = 0.5f * s * (1.f + erff(s * 0.70710678118654752f));
    }
    for (int w2 = 0; w2 < 4; ++w2) {
      float s = l2_b[w2];
      for (int i2 = 0; i2 < 16; ++i2) s += l2_w[w2 * 16 + i2] * h1[i2];
      ww[b * 4 + w2] = 1.f / (1.f + expf(-s));
    }
  }
}

// K3: A[w,o,m] = sum_oc fusion_w[o, w*128+oc]*cw[w,oc,m]; P same with fusion_w[o,512+oc]
//     m = c*9+t in [0,1152). Thread computes a float4 of m for one (w,o).
__global__ void k3_AP(const float* __restrict__ fusion_w, const float* __restrict__ conv1_w,
                      float* __restrict__ A, float* __restrict__ P) {
  int gid = blockIdx.x * 256 + threadIdx.x;   // 0..147455
  int w = gid / 36864;
  int rem = gid % 36864;
  int o = rem / 288;
  int m = (rem % 288) * 4;
  const float* fw1 = fusion_w + o * 640 + w * 128;
  const float* fw4 = fusion_w + o * 640 + 512;
  const float* cw = conv1_w + (size_t)w * 128 * 1152 + m;
  float a0 = 0, a1 = 0, a2 = 0, a3 = 0, p0 = 0, p1 = 0, p2 = 0, p3 = 0;
  for (int oc = 0; oc < 128; ++oc) {
    float f1 = fw1[oc], f4 = fw4[oc];
    float4 cv = *(const float4*)(cw + (size_t)oc * 1152);
    a0 += f1 * cv.x; a1 += f1 * cv.y; a2 += f1 * cv.z; a3 += f1 * cv.w;
    p0 += f4 * cv.x; p1 += f4 * cv.y; p2 += f4 * cv.z; p3 += f4 * cv.w;
  }
  float4* Ao = (float4*)(A + (size_t)(w * 128 + o) * 1152 + m);
  float4* Po = (float4*)(P + (size_t)(w * 128 + o) * 1152 + m);
  *Ao = make_float4(a0, a1, a2, a3);
  *Po = make_float4(p0, p1, p2, p3);
}

// K4: M[w][t][o][c] = A[w,o,c*9+t] + sum_j P[w,o,j*9+t] * gkT[w][j][c]
__global__ void k4_M(const float* __restrict__ A, const float* __restrict__ P,
                     const float* __restrict__ gkT, float* __restrict__ M) {
  int gid = blockIdx.x * 256 + threadIdx.x;   // 0..147455
  int w = gid / 36864;
  int rem = gid % 36864;
  int t = rem / 4096;
  int o = (rem % 4096) / 32;
  int c = (rem % 32) * 4;
  const float* Pp = P + (size_t)(w * 128 + o) * 1152 + t;
  const float* Ap = A + (size_t)(w * 128 + o) * 1152 + t;
  const float* g = gkT + w * 16384 + c;
  float acc0 = Ap[(c + 0) * 9], acc1 = Ap[(c + 1) * 9];
  float acc2 = Ap[(c + 2) * 9], acc3 = Ap[(c + 3) * 9];
  for (int j = 0; j < 128; ++j) {
    float pv = Pp[j * 9];
    float4 gv = *(const float4*)(g + j * 128);
    acc0 += pv * gv.x; acc1 += pv * gv.y; acc2 += pv * gv.z; acc3 += pv * gv.w;
  }
  *(float4*)(M + (size_t)((w * 9 + t) * 128 + o) * 128 + c) = make_float4(acc0, acc1, acc2, acc3);
}

// K5: Keff_bf16[b][t][o][c] = sum_w ww[b,w]*M[w][t][o][c] + fsum[o]*gk_b[c]
__global__ void k5_keff(const float* __restrict__ M, const float* __restrict__ ww,
                        const float* __restrict__ fsum, const float* __restrict__ gk_b,
                        u16* __restrict__ keff) {
  int gid = blockIdx.x * 256 + threadIdx.x;   // 0..294911
  int b = gid / 36864;
  int rem = gid % 36864;                      // t*4096 + o*32 + cq
  int o = (rem % 4096) / 32;
  int c = (rem % 32) * 4;
  float w0 = ww[b * 4 + 0], w1 = ww[b * 4 + 1], w2 = ww[b * 4 + 2], w3 = ww[b * 4 + 3];
  int mi = rem * 4;                           // == t*16384 + o*128 + c
  float4 m0 = *(const float4*)(M + 0 * 147456 + mi);
  float4 m1 = *(const float4*)(M + 1 * 147456 + mi);
  float4 m2 = *(const float4*)(M + 2 * 147456 + mi);
  float4 m3 = *(const float4*)(M + 3 * 147456 + mi);
  float fs = fsum[o];
  float4 gb = *(const float4*)(gk_b + c);
  float r0 = w0 * m0.x + w1 * m1.x + w2 * m2.x + w3 * m3.x + fs * gb.x;
  float r1 = w0 * m0.y + w1 * m1.y + w2 * m2.y + w3 * m3.y + fs * gb.y;
  float r2 = w0 * m0.z + w1 * m1.z + w2 * m2.z + w3 * m3.z + fs * gb.z;
  float r3 = w0 * m0.w + w1 * m1.w + w2 * m2.w + w3 * m3.w + fs * gb.w;
  u16x4 st = { f2bf(r0), f2bf(r1), f2bf(r2), f2bf(r3) };
  *(u16x4*)(keff + (size_t)b * 147456 + mi) = st;
}

// K6: per-batch 3x3 C->C conv as 9 accumulated bf16 MFMA GEMMs.
// Occupancy build: block = (b, image row p, o-half nh): out tile 128 pixels x 64 o.
// LDS = 2 x 16 KB weight slices (double-buffered) = 32 KB -> 5 blocks/CU (20 waves)
// vs previous 64 KB / 2 blocks. Latency-bound kernel -> more resident blocks to
// interleave barrier stalls and L2-load latency across blocks.
// 4 waves in 2x2: wave tile 64 m x 32 n, acc[4][2].
// T2 XOR-swizzle on the weight slice (elem off ^ ((row&7)<<3)) on BOTH write and read.
__global__ __launch_bounds__(256, 5) void k6_conv(
    const u16* __restrict__ xpad, const u16* __restrict__ keff,
    const float* __restrict__ fusion_b, float* __restrict__ out) {
  __shared__ __align__(16) u16 wlds[2][64 * 128];
  const int tid = threadIdx.x;
  const int blk = blockIdx.x;
  const int b = blk & 7;            // XCD affinity: batch <-> XCD
  const int rh = blk >> 3;          // 0..255
  const int p = rh >> 1;            // image row
  const int nh = rh & 1;            // o-half: o in [nh*64, nh*64+64)
  const int wid = tid >> 6;
  const int lane = tid & 63;
  const int wm = (wid & 1) * 64;
  const int wn = (wid >> 1) * 32;   // local o offset within the 64-slice
  const int quad = lane >> 4;
  const int l16 = lane & 15;

  f32x4 acc[4][2];
  #pragma unroll
  for (int i = 0; i < 4; ++i)
    #pragma unroll
    for (int j = 0; j < 2; ++j)
      acc[i][j] = (f32x4){0.f, 0.f, 0.f, 0.f};

  // this block's keff slice: rows [nh*64, nh*64+64) of each tap
  const u16* kb = keff + (size_t)b * 147456 + (size_t)nh * 8192;
  bf16x8 streg[4];

  auto stage_load = [&](int tap) {
    const u16* src = kb + tap * 16384;
    #pragma unroll
    for (int it = 0; it < 4; ++it)
      streg[it] = *(const bf16x8*)(src + (it * 256 + tid) * 8);
  };
  // swizzled write: idx = linear 16B-chunk index (0..1023); row = idx>>4 (16 chunks/row)
  auto stage_write = [&](int bufi) {
    u16* dst = &wlds[bufi][0];
    #pragma unroll
    for (int it = 0; it < 4; ++it) {
      const int idx = it * 256 + tid;
      const int off = (idx * 8) ^ (((idx >> 4) & 7) << 3);
      *(bf16x8*)(dst + off) = streg[it];
    }
  };

  stage_load(0);
  stage_write(0);
  __syncthreads();

  const size_t xrow = 130 * 128;
  const u16* xb = xpad + (size_t)b * 130 * xrow;

  for (int tap = 0; tap < 9; ++tap) {
    if (tap < 8) stage_load(tap + 1);           // overlaps with MFMA below
    const int dh = tap / 3 - 1;
    const int dw = tap % 3 - 1;
    const u16* arow = xb + (size_t)(p + 1 + dh) * xrow + (size_t)(1 + dw) * 128;
    const u16* wbuf = &wlds[tap & 1][0];
    #pragma unroll
    for (int kc = 0; kc < 4; ++kc) {
      const int c0 = kc * 32 + quad * 8;
      bf16x8 a[4], bb[2];
      #pragma unroll
      for (int i = 0; i < 4; ++i)
        a[i] = *(const bf16x8*)(arow + (size_t)(wm + i * 16 + l16) * 128 + c0);
      #pragma unroll
      for (int j = 0; j < 2; ++j) {
        const int row = wn + j * 16 + l16;      // local row 0..63
        const int off = (row * 128 + c0) ^ ((row & 7) << 3);
        bb[j] = *(const bf16x8*)(wbuf + off);
      }
      #pragma unroll
      for (int i = 0; i < 4; ++i)
        #pragma unroll
        for (int j = 0; j < 2; ++j)
          acc[i][j] = __builtin_amdgcn_mfma_f32_16x16x32_bf16(a[i], bb[j], acc[i][j], 0, 0, 0);
    }
    if (tap < 8) stage_write((tap + 1) & 1);
    __syncthreads();
  }

  float fb[2];
  #pragma unroll
  for (int j = 0; j < 2; ++j) fb[j] = fusion_b[nh * 64 + wn + j * 16 + l16];
  float* outb = out + ((size_t)b * 16384 + (size_t)p * 128) * 128;
  #pragma unroll
  for (int i = 0; i < 4; ++i)
    #pragma unroll
    for (int r = 0; r < 4; ++r) {
      const int m = wm + i * 16 + quad * 4 + r;
      #pragma unroll
      for (int j = 0; j < 2; ++j)
        outb[(size_t)m * 128 + (nh * 64 + wn + j * 16 + l16)] = acc[i][j][r] + fb[j];
    }
}

extern "C" void kernel_launch(void* const* d_in, const int* in_sizes, int n_in,
                              void* d_out, int out_size, void* d_ws, size_t ws_size,
                              hipStream_t stream) {
  const float* x        = (const float*)d_in[0];
  const float* conv1_w  = (const float*)d_in[1];
  const float* dc_w     = (const float*)d_in[2];
  const float* dc_b     = (const float*)d_in[3];
  const float* l1_w     = (const float*)d_in[4];
  const float* l1_b     = (const float*)d_in[5];
  const float* l2_w     = (const float*)d_in[6];
  const float* l2_b     = (const float*)d_in[7];
  const float* gk_w     = (const float*)d_in[8];
  const float* gk_b     = (const float*)d_in[9];
  const float* fusion_w = (const float*)d_in[10];
  const float* fusion_b = (const float*)d_in[11];
  float* out = (float*)d_out;
  char* ws = (char*)d_ws;

  float* agg  = (float*)(ws + OFF_AGG);
  float* ww   = (float*)(ws + OFF_WW);
  float* R    = (float*)(ws + OFF_R);
  float* fsum = (float*)(ws + OFF_FSUM);
  float* gkT  = (float*)(ws + OFF_GKT);
  float* A    = (float*)(ws + OFF_A);
  float* P    = (float*)(ws + OFF_P);
  float* M    = (float*)(ws + OFF_M);
  u16* keff   = (u16*)(ws + OFF_KEFF);
  u16* xpad   = (u16*)(ws + OFF_XPAD);

  hipMemsetAsync(agg, 0, 81920, stream);
  k1_pad_agg<<<dim3(130, 8), 128, 0, stream>>>(x, xpad, agg);
  kR<<<18, 256, 0, stream>>>(dc_w, conv1_w, R);
  kT<<<256, 256, 0, stream>>>(gk_w, gkT);
  kF<<<1, 128, 0, stream>>>(fusion_w, fsum);
  k2_ww<<<8, 256, 0, stream>>>(x, agg, R, dc_b, l1_w, l1_b, l2_w, l2_b, ww);
  k3_AP<<<576, 256, 0, stream>>>(fusion_w, conv1_w, A, P);
  k4_M<<<576, 256, 0, stream>>>(A, P, gkT, M);
  k5_keff<<<1152, 256, 0, stream>>>(M, ww, fsum, gk_b, keff);
  k6_conv<<<2048, 256, 0, stream>>>(xpad, keff, fusion_b, out);
}

// Round 3
// 262.946 us; speedup vs baseline: 1.3981x; 1.3981x over previous
//
#include <hip/hip_runtime.h>
#include <hip/hip_bf16.h>
#include <cmath>

typedef unsigned short u16;
typedef __attribute__((ext_vector_type(8))) short bf16x8;
typedef __attribute__((ext_vector_type(4))) float f32x4;
typedef __attribute__((ext_vector_type(4))) unsigned short u16x4;

// Problem constants: B=8, C=128, H=128, WIN=4, K=3, WS=64, L=16384
// Workspace layout (bytes):
#define OFF_AGG   0u          // 5 stats * 8b * 4w * 128c f32 = 81920
#define OFF_WW    81920u      // 32 f32
#define OFF_R     82048u      // 4*128*9 f32 = 18432
#define OFF_FSUM  100480u     // 128 f32
#define OFF_GKT   100992u     // 4*128*128 f32 = 262144
#define OFF_A     363136u     // 4*128*1152 f32 = 2359296
#define OFF_P     2722432u    // 2359296
#define OFF_M     5081728u    // [w][t][o][c] f32 = 2359296
#define OFF_KEFF  7441024u    // [b][t][o][c] u16 = 2359296
#define OFF_XPAD  9800320u    // [b][130][130][128] u16 = 34611200  (total ~42.4 MB)

__device__ __forceinline__ u16 f2bf(float f) {
  union { float f; unsigned int u; } v; v.f = f;
  unsigned int r = v.u + 0x7FFFu + ((v.u >> 16) & 1u);
  return (u16)(r >> 16);
}

// K1: fp32 x -> padded bf16 image [b][130][130][128]; window boundary aggregates via atomics.
// agg stats: 0=T 1=rowFirst 2=rowLast 3=colFirst 4=colLast, layout [stat][b][w][c]
__global__ void k1_pad_agg(const float* __restrict__ x, u16* __restrict__ xpad,
                           float* __restrict__ agg) {
  const int c = threadIdx.x;      // 0..127
  const int rp = blockIdx.x;      // padded row 0..129
  const int b = blockIdx.y;
  const size_t xpb = ((size_t)b * 130 + rp) * 130 * 128;
  if (rp == 0 || rp == 129) {
    for (int q = 0; q < 130; ++q) xpad[xpb + (size_t)q * 128 + c] = 0;
    return;
  }
  const int r = rp - 1;
  xpad[xpb + c] = 0;
  xpad[xpb + (size_t)129 * 128 + c] = 0;
  const float* xr = x + ((size_t)b * 16384 + (size_t)r * 128) * 128 + c;
  float t0 = 0.f, t1 = 0.f, cF0 = 0.f, cL0 = 0.f, cF1 = 0.f, cL1 = 0.f;
  #pragma unroll 4
  for (int q = 0; q < 128; ++q) {
    float v = xr[(size_t)q * 128];
    xpad[xpb + (size_t)(q + 1) * 128 + c] = f2bf(v);
    if (q < 64) t0 += v; else t1 += v;
    if (q == 0) cF0 = v;
    if (q == 63) cL0 = v;
    if (q == 64) cF1 = v;
    if (q == 127) cL1 = v;
  }
  const int i = r >> 6, rw = r & 63;
  const int a0 = b * 512 + (i * 2) * 128 + c;
  const int a1 = b * 512 + (i * 2 + 1) * 128 + c;
  atomicAdd(&agg[a0], t0);
  atomicAdd(&agg[a1], t1);
  atomicAdd(&agg[3 * 4096 + a0], cF0);
  atomicAdd(&agg[3 * 4096 + a1], cF1);
  atomicAdd(&agg[4 * 4096 + a0], cL0);
  atomicAdd(&agg[4 * 4096 + a1], cL1);
  if (rw == 0)  { atomicAdd(&agg[4096 + a0], t0); atomicAdd(&agg[4096 + a1], t1); }
  if (rw == 63) { atomicAdd(&agg[2 * 4096 + a0], t0); atomicAdd(&agg[2 * 4096 + a1], t1); }
}

// R[w,c,t] = sum_o dc_w[w,o] * conv1_w[w*128+o, c, t]    (4608 outputs, K=128)
__global__ void kR(const float* __restrict__ dc_w, const float* __restrict__ conv1_w,
                   float* __restrict__ R) {
  int gid = blockIdx.x * 256 + threadIdx.x;   // 0..4607
  int w = gid / 1152, m = gid % 1152;
  float s = 0.f;
  for (int o = 0; o < 128; ++o)
    s += dc_w[w * 128 + o] * conv1_w[(size_t)(w * 128 + o) * 1152 + m];
  R[gid] = s;
}

// gkT[w][j][c] = gk_w[c][w][j]
__global__ void kT(const float* __restrict__ gk_w, float* __restrict__ gkT) {
  int gid = blockIdx.x * 256 + threadIdx.x;   // 0..65535
  int w = gid >> 14, j = (gid >> 7) & 127, c = gid & 127;
  gkT[gid] = gk_w[c * 512 + w * 128 + j];
}

// fsum[o] = sum_oc fusion_w[o, 512+oc]
__global__ void kF(const float* __restrict__ fusion_w, float* __restrict__ fsum) {
  int o = threadIdx.x;
  float s = 0.f;
  for (int oc = 0; oc < 128; ++oc) s += fusion_w[o * 640 + 512 + oc];
  fsum[o] = s;
}

// K2: per-batch SE gate ww[b][w] from aggregates (S trick) + exact-gelu MLP + sigmoid
__global__ void k2_ww(const float* __restrict__ x, const float* __restrict__ agg,
                      const float* __restrict__ R, const float* __restrict__ dc_b,
                      const float* __restrict__ l1_w, const float* __restrict__ l1_b,
                      const float* __restrict__ l2_w, const float* __restrict__ l2_b,
                      float* __restrict__ ww) {
  const int b = blockIdx.x;
  const int tid = threadIdx.x;
  const int w = tid >> 6, lane = tid & 63;
  __shared__ float red[4];
  float partial = 0.f;
  const int i = w >> 1, j = w & 1;
  const int r0 = i * 64, s0 = j * 64;
  const size_t base = (size_t)b * 16384 * 128;
  #pragma unroll
  for (int k = 0; k < 2; ++k) {
    const int c = lane * 2 + k;
    const int ai = b * 512 + w * 128 + c;
    float T  = agg[ai];
    float rF = agg[4096 + ai];
    float rL = agg[2 * 4096 + ai];
    float cF = agg[3 * 4096 + ai];
    float cL = agg[4 * 4096 + ai];
    float c00 = x[base + ((size_t)(r0 + 0)  * 128 + (s0 + 0))  * 128 + c];
    float c0L = x[base + ((size_t)(r0 + 0)  * 128 + (s0 + 63)) * 128 + c];
    float cL0 = x[base + ((size_t)(r0 + 63) * 128 + (s0 + 0))  * 128 + c];
    float cLL = x[base + ((size_t)(r0 + 63) * 128 + (s0 + 63)) * 128 + c];
    float S[9];
    S[0] = T - rL - cL + cLL;
    S[1] = T - rL;
    S[2] = T - rL - cF + cL0;
    S[3] = T - cL;
    S[4] = T;
    S[5] = T - cF;
    S[6] = T - rF - cL + c0L;
    S[7] = T - rF;
    S[8] = T - rF - cF + c00;
    const float* Rp = R + (w * 128 + c) * 9;
    #pragma unroll
    for (int t = 0; t < 9; ++t) partial += S[t] * Rp[t];
  }
  for (int off = 32; off > 0; off >>= 1) partial += __shfl_xor(partial, off, 64);
  if (lane == 0) red[w] = partial;
  __syncthreads();
  if (tid == 0) {
    float ww0[4];
    #pragma unroll
    for (int w2 = 0; w2 < 4; ++w2) ww0[w2] = red[w2] * (1.f / 4096.f) + dc_b[w2];
    float h1[16];
    for (int i2 = 0; i2 < 16; ++i2) {
      float s = l1_b[i2];
      #pragma unroll
      for (int w2 = 0; w2 < 4; ++w2) s += l1_w[i2 * 4 + w2] * ww0[w2];
      h1[i2] = 0.5f * s * (1.f + erff(s * 0.70710678118654752f));
    }
    for (int w2 = 0; w2 < 4; ++w2) {
      float s = l2_b[w2];
      for (int i2 = 0; i2 < 16; ++i2) s += l2_w[w2 * 16 + i2] * h1[i2];
      ww[b * 4 + w2] = 1.f / (1.f + expf(-s));
    }
  }
}

// K3: A[w,o,m] = sum_oc fusion_w[o, w*128+oc]*cw[w,oc,m]; P same with fusion_w[o,512+oc]
//     m = c*9+t in [0,1152). Thread computes a float4 of m for one (w,o).
__global__ void k3_AP(const float* __restrict__ fusion_w, const float* __restrict__ conv1_w,
                      float* __restrict__ A, float* __restrict__ P) {
  int gid = blockIdx.x * 256 + threadIdx.x;   // 0..147455
  int w = gid / 36864;
  int rem = gid % 36864;
  int o = rem / 288;
  int m = (rem % 288) * 4;
  const float* fw1 = fusion_w + o * 640 + w * 128;
  const float* fw4 = fusion_w + o * 640 + 512;
  const float* cw = conv1_w + (size_t)w * 128 * 1152 + m;
  float a0 = 0, a1 = 0, a2 = 0, a3 = 0, p0 = 0, p1 = 0, p2 = 0, p3 = 0;
  for (int oc = 0; oc < 128; ++oc) {
    float f1 = fw1[oc], f4 = fw4[oc];
    float4 cv = *(const float4*)(cw + (size_t)oc * 1152);
    a0 += f1 * cv.x; a1 += f1 * cv.y; a2 += f1 * cv.z; a3 += f1 * cv.w;
    p0 += f4 * cv.x; p1 += f4 * cv.y; p2 += f4 * cv.z; p3 += f4 * cv.w;
  }
  float4* Ao = (float4*)(A + (size_t)(w * 128 + o) * 1152 + m);
  float4* Po = (float4*)(P + (size_t)(w * 128 + o) * 1152 + m);
  *Ao = make_float4(a0, a1, a2, a3);
  *Po = make_float4(p0, p1, p2, p3);
}

// K4: M[w][t][o][c] = A[w,o,c*9+t] + sum_j P[w,o,j*9+t] * gkT[w][j][c]
__global__ void k4_M(const float* __restrict__ A, const float* __restrict__ P,
                     const float* __restrict__ gkT, float* __restrict__ M) {
  int gid = blockIdx.x * 256 + threadIdx.x;   // 0..147455
  int w = gid / 36864;
  int rem = gid % 36864;
  int t = rem / 4096;
  int o = (rem % 4096) / 32;
  int c = (rem % 32) * 4;
  const float* Pp = P + (size_t)(w * 128 + o) * 1152 + t;
  const float* Ap = A + (size_t)(w * 128 + o) * 1152 + t;
  const float* g = gkT + w * 16384 + c;
  float acc0 = Ap[(c + 0) * 9], acc1 = Ap[(c + 1) * 9];
  float acc2 = Ap[(c + 2) * 9], acc3 = Ap[(c + 3) * 9];
  for (int j = 0; j < 128; ++j) {
    float pv = Pp[j * 9];
    float4 gv = *(const float4*)(g + j * 128);
    acc0 += pv * gv.x; acc1 += pv * gv.y; acc2 += pv * gv.z; acc3 += pv * gv.w;
  }
  *(float4*)(M + (size_t)((w * 9 + t) * 128 + o) * 128 + c) = make_float4(acc0, acc1, acc2, acc3);
}

// K5: Keff_bf16[b][t][o][c] = sum_w ww[b,w]*M[w][t][o][c] + fsum[o]*gk_b[c]
__global__ void k5_keff(const float* __restrict__ M, const float* __restrict__ ww,
                        const float* __restrict__ fsum, const float* __restrict__ gk_b,
                        u16* __restrict__ keff) {
  int gid = blockIdx.x * 256 + threadIdx.x;   // 0..294911
  int b = gid / 36864;
  int rem = gid % 36864;                      // t*4096 + o*32 + cq
  int o = (rem % 4096) / 32;
  int c = (rem % 32) * 4;
  float w0 = ww[b * 4 + 0], w1 = ww[b * 4 + 1], w2 = ww[b * 4 + 2], w3 = ww[b * 4 + 3];
  int mi = rem * 4;                           // == t*16384 + o*128 + c
  float4 m0 = *(const float4*)(M + 0 * 147456 + mi);
  float4 m1 = *(const float4*)(M + 1 * 147456 + mi);
  float4 m2 = *(const float4*)(M + 2 * 147456 + mi);
  float4 m3 = *(const float4*)(M + 3 * 147456 + mi);
  float fs = fsum[o];
  float4 gb = *(const float4*)(gk_b + c);
  float r0 = w0 * m0.x + w1 * m1.x + w2 * m2.x + w3 * m3.x + fs * gb.x;
  float r1 = w0 * m0.y + w1 * m1.y + w2 * m2.y + w3 * m3.y + fs * gb.y;
  float r2 = w0 * m0.z + w1 * m1.z + w2 * m2.z + w3 * m3.z + fs * gb.z;
  float r3 = w0 * m0.w + w1 * m1.w + w2 * m2.w + w3 * m3.w + fs * gb.w;
  u16x4 st = { f2bf(r0), f2bf(r1), f2bf(r2), f2bf(r3) };
  *(u16x4*)(keff + (size_t)b * 147456 + mi) = st;
}

// K6: per-batch 3x3 C->C conv as 9 accumulated bf16 MFMA GEMMs.
// Block = (b, image row p): out tile 128 pixels x 128 o; 4 waves in 2x2 (64m x 64n each).
// BOTH operands staged in LDS (the previous global scattered A-fragment loads were the
// bottleneck: 16 discontiguous 64B segments per load instr saturated the TA).
//  - A: one padded image row (130 px x 128 c bf16 = 33,280 B), staged once per dh-group
//       (3 taps share it) via global_load_lds DMA with PRE-SWIZZLED GLOBAL addresses
//       (LDS dest linear; swizzle is the involution chunk ^= ((chunk>>4)&7) on 16B chunks).
//  - W: 32 KB/tap, single-buffered, reg-staged (loads overlap compute, write after barrier),
//       same (linear-LDS, swizzled-source) convention.
// Reads of both use off = lin ^ ((row&7)<<3), giving uniform minimal bank spread.
// LDS total 66,560 B -> 2 blocks/CU.
__global__ __launch_bounds__(256, 2) void k6_conv(
    const u16* __restrict__ xpad, const u16* __restrict__ keff,
    const float* __restrict__ fusion_b, float* __restrict__ out) {
  __shared__ __align__(16) u16 alds[130 * 128];   // 33,280 B
  __shared__ __align__(16) u16 apad[256];         // 512 B guard for masked DMA tail
  __shared__ __align__(16) u16 wlds[128 * 128];   // 32,768 B
  const int tid = threadIdx.x;
  const int blk = blockIdx.x;
  const int b = blk & 7;            // XCD affinity: batch <-> XCD
  const int p = blk >> 3;
  const int wid = tid >> 6;
  const int lane = tid & 63;
  const int wm = (wid & 1) * 64;
  const int wn = (wid >> 1) * 64;
  const int quad = lane >> 4;
  const int l16 = lane & 15;

  f32x4 acc[4][4];
  #pragma unroll
  for (int i = 0; i < 4; ++i)
    #pragma unroll
    for (int j = 0; j < 4; ++j)
      acc[i][j] = (f32x4){0.f, 0.f, 0.f, 0.f};

  const u16* kb = keff + (size_t)b * 147456;
  const u16* xb = xpad + (size_t)b * 130 * 16640;
  bf16x8 streg[8];
  (void)apad;

  auto stage_W_load = [&](int tap) {
    const u16* src = kb + tap * 16384;
    #pragma unroll
    for (int it = 0; it < 8; ++it) {
      const int chunk = it * 256 + tid;
      const int gs = chunk ^ ((chunk >> 4) & 7);
      streg[it] = *(const bf16x8*)(src + gs * 8);
    }
  };
  auto stage_W_write = [&]() {
    #pragma unroll
    for (int it = 0; it < 8; ++it)
      *(bf16x8*)(wlds + (it * 256 + tid) * 8) = streg[it];
  };
  // A-row DMA: 2080 16B chunks (pixels 0..129). 8 full-wave rounds per wave cover 2048;
  // tail 32 chunks by lanes 0..31 of wave 0 (apad guards any exec-mask surprise).
  auto stage_A_dma = [&](int prow) {
    const u16* src = xb + (size_t)prow * 16640;
    #pragma unroll
    for (int r = 0; r < 8; ++r) {
      const int chunk = (wid * 8 + r) * 64 + lane;
      const int gs = chunk ^ ((chunk >> 4) & 7);
      __builtin_amdgcn_global_load_lds(
          (const __attribute__((address_space(1))) unsigned int*)(src + (size_t)gs * 8),
          (__attribute__((address_space(3))) unsigned int*)(alds + (wid * 8 + r) * 512),
          16, 0, 0);
    }
    if (tid < 32) {
      const int chunk = 2048 + tid;
      const int gs = chunk ^ ((chunk >> 4) & 7);
      __builtin_amdgcn_global_load_lds(
          (const __attribute__((address_space(1))) unsigned int*)(src + (size_t)gs * 8),
          (__attribute__((address_space(3))) unsigned int*)(alds + 2048 * 8),
          16, 0, 0);
    }
  };

  // Prologue: stage W tap0 (regs) + DMA A row for dh=-1 (padded row p), then commit.
  stage_W_load(0);
  stage_A_dma(p);
  stage_W_write();
  __syncthreads();   // drains vmcnt -> DMA complete, W visible

  for (int tap = 0; tap < 9; ++tap) {
    if (tap < 8) stage_W_load(tap + 1);         // global->reg, overlaps MFMA
    const int dw = tap % 3 - 1;
    const int pixoff = 1 + dw;
    #pragma unroll
    for (int kc = 0; kc < 4; ++kc) {
      const int c0 = kc * 32 + quad * 8;
      bf16x8 a[4], bb[4];
      #pragma unroll
      for (int i = 0; i < 4; ++i) {
        const int pix = pixoff + wm + i * 16 + l16;
        const int off = (pix * 128 + c0) ^ ((pix & 7) << 3);
        a[i] = *(const bf16x8*)(alds + off);
      }
      #pragma unroll
      for (int j = 0; j < 4; ++j) {
        const int row = wn + j * 16 + l16;
        const int off = (row * 128 + c0) ^ ((row & 7) << 3);
        bb[j] = *(const bf16x8*)(wlds + off);
      }
      #pragma unroll
      for (int i = 0; i < 4; ++i)
        #pragma unroll
        for (int j = 0; j < 4; ++j)
          acc[i][j] = __builtin_amdgcn_mfma_f32_16x16x32_bf16(a[i], bb[j], acc[i][j], 0, 0, 0);
    }
    __syncthreads();                            // all waves done reading alds/wlds
    if (tap < 8) {
      stage_W_write();                          // vmcnt waits streg, then ds_write
      if (tap % 3 == 2) stage_A_dma(p + (tap + 1) / 3);  // next dh row
      __syncthreads();                          // drains vmcnt -> DMA + writes visible
    }
  }

  float fb[4];
  #pragma unroll
  for (int j = 0; j < 4; ++j) fb[j] = fusion_b[wn + j * 16 + l16];
  float* outb = out + ((size_t)b * 16384 + (size_t)p * 128) * 128;
  #pragma unroll
  for (int i = 0; i < 4; ++i)
    #pragma unroll
    for (int r = 0; r < 4; ++r) {
      const int m = wm + i * 16 + quad * 4 + r;
      #pragma unroll
      for (int j = 0; j < 4; ++j)
        outb[(size_t)m * 128 + (wn + j * 16 + l16)] = acc[i][j][r] + fb[j];
    }
}

extern "C" void kernel_launch(void* const* d_in, const int* in_sizes, int n_in,
                              void* d_out, int out_size, void* d_ws, size_t ws_size,
                              hipStream_t stream) {
  const float* x        = (const float*)d_in[0];
  const float* conv1_w  = (const float*)d_in[1];
  const float* dc_w     = (const float*)d_in[2];
  const float* dc_b     = (const float*)d_in[3];
  const float* l1_w     = (const float*)d_in[4];
  const float* l1_b     = (const float*)d_in[5];
  const float* l2_w     = (const float*)d_in[6];
  const float* l2_b     = (const float*)d_in[7];
  const float* gk_w     = (const float*)d_in[8];
  const float* gk_b     = (const float*)d_in[9];
  const float* fusion_w = (const float*)d_in[10];
  const float* fusion_b = (const float*)d_in[11];
  float* out = (float*)d_out;
  char* ws = (char*)d_ws;

  float* agg  = (float*)(ws + OFF_AGG);
  float* ww   = (float*)(ws + OFF_WW);
  float* R    = (float*)(ws + OFF_R);
  float* fsum = (float*)(ws + OFF_FSUM);
  float* gkT  = (float*)(ws + OFF_GKT);
  float* A    = (float*)(ws + OFF_A);
  float* P    = (float*)(ws + OFF_P);
  float* M    = (float*)(ws + OFF_M);
  u16* keff   = (u16*)(ws + OFF_KEFF);
  u16* xpad   = (u16*)(ws + OFF_XPAD);

  hipMemsetAsync(agg, 0, 81920, stream);
  k1_pad_agg<<<dim3(130, 8), 128, 0, stream>>>(x, xpad, agg);
  kR<<<18, 256, 0, stream>>>(dc_w, conv1_w, R);
  kT<<<256, 256, 0, stream>>>(gk_w, gkT);
  kF<<<1, 128, 0, stream>>>(fusion_w, fsum);
  k2_ww<<<8, 256, 0, stream>>>(x, agg, R, dc_b, l1_w, l1_b, l2_w, l2_b, ww);
  k3_AP<<<576, 256, 0, stream>>>(fusion_w, conv1_w, A, P);
  k4_M<<<576, 256, 0, stream>>>(A, P, gkT, M);
  k5_keff<<<1152, 256, 0, stream>>>(M, ww, fsum, gk_b, keff);
  k6_conv<<<1024, 256, 0, stream>>>(xpad, keff, fusion_b, out);
}

// Round 4
// 246.125 us; speedup vs baseline: 1.4936x; 1.0683x over previous
//
#include <hip/hip_runtime.h>
#include <hip/hip_bf16.h>
#include <cmath>

typedef unsigned short u16;
typedef __attribute__((ext_vector_type(8))) short bf16x8;
typedef __attribute__((ext_vector_type(4))) float f32x4;
typedef __attribute__((ext_vector_type(4))) unsigned short u16x4;

// Problem constants: B=8, C=128, H=128, WIN=4, K=3, WS=64, L=16384
// Workspace layout (bytes):
#define OFF_AGG   0u          // 5 stats * 8b * 4w * 128c f32 = 81920
#define OFF_WW    81920u      // 32 f32
#define OFF_R     82048u      // 4*128*9 f32 = 18432
#define OFF_FSUM  100480u     // 128 f32
#define OFF_GKT   100992u     // 4*128*128 f32 = 262144
#define OFF_A     363136u     // 4*128*1152 f32 = 2359296
#define OFF_P     2722432u    // 2359296
#define OFF_M     5081728u    // (unused since k4/k5 fusion; kept for layout stability)
#define OFF_KEFF  7441024u    // [b][t][o][c] u16 = 2359296
#define OFF_XPAD  9800320u    // [b][130][130][128] u16 = 34611200  (total ~42.4 MB)

__device__ __forceinline__ u16 f2bf(float f) {
  union { float f; unsigned int u; } v; v.f = f;
  unsigned int r = v.u + 0x7FFFu + ((v.u >> 16) & 1u);
  return (u16)(r >> 16);
}

// K1 (vectorized): fp32 x -> padded bf16 image [b][130][130][128] + window boundary aggregates.
// Block = (padded row rp, b), 256 threads: strip s = tid>>5 owns 16 pixels, cg = tid&31 owns
// 4 channels (f32x4 load / u16x4 store). Window sums reduced via LDS, one atomic per (w,c,stat).
// agg stats: 0=T 1=rowFirst 2=rowLast 3=colFirst 4=colLast, layout [stat][b][w][c]
__global__ void k1_pad_agg(const float* __restrict__ x, u16* __restrict__ xpad,
                           float* __restrict__ agg) {
  const int rp = blockIdx.x;      // padded row 0..129
  const int b = blockIdx.y;
  const int tid = threadIdx.x;
  const size_t xpb = ((size_t)b * 130 + rp) * 16640;
  if (rp == 0 || rp == 129) {
    const bf16x8 z = {0, 0, 0, 0, 0, 0, 0, 0};
    #pragma unroll
    for (int rr = 0; rr < 8; ++rr)
      *(bf16x8*)(xpad + xpb + (size_t)(rr * 256 + tid) * 8) = z;
    if (tid < 32)
      *(bf16x8*)(xpad + xpb + (size_t)(2048 + tid) * 8) = z;
    return;
  }
  const int r = rp - 1;
  // side pads (px 0 and px 129)
  if (tid < 32) {
    *(u16x4*)(xpad + xpb + tid * 4) = (u16x4){0, 0, 0, 0};
  } else if (tid < 64) {
    *(u16x4*)(xpad + xpb + 129 * 128 + (tid - 32) * 4) = (u16x4){0, 0, 0, 0};
  }
  const int s = tid >> 5;          // pixel strip 0..7 (16 px each)
  const int cg = tid & 31;         // channel group
  const int c0 = cg * 4;
  const float* xr = x + ((size_t)b * 16384 + (size_t)r * 128) * 128;
  f32x4 sum = {0.f, 0.f, 0.f, 0.f};
  f32x4 cap = {0.f, 0.f, 0.f, 0.f};  // col-first (s==0/4) or col-last (s==3/7) capture
  #pragma unroll
  for (int qi = 0; qi < 16; ++qi) {
    const int q = s * 16 + qi;
    f32x4 v = *(const f32x4*)(xr + (size_t)q * 128 + c0);
    sum += v;
    if (qi == 0 && (s == 0 || s == 4)) cap = v;   // q == 0 / 64
    if (qi == 15 && (s == 3 || s == 7)) cap = v;  // q == 63 / 127
    u16x4 st = { f2bf(v[0]), f2bf(v[1]), f2bf(v[2]), f2bf(v[3]) };
    *(u16x4*)(xpad + xpb + (size_t)(q + 1) * 128 + c0) = st;
  }
  const int i = r >> 6, rw = r & 63;
  const int abase = b * 512 + c0;
  // column stats: single row value per (b,w,c), accumulated over rows via atomics
  if (s == 0) {
    #pragma unroll
    for (int k = 0; k < 4; ++k) atomicAdd(&agg[3 * 4096 + abase + (i * 2) * 128 + k], cap[k]);
  } else if (s == 4) {
    #pragma unroll
    for (int k = 0; k < 4; ++k) atomicAdd(&agg[3 * 4096 + abase + (i * 2 + 1) * 128 + k], cap[k]);
  } else if (s == 3) {
    #pragma unroll
    for (int k = 0; k < 4; ++k) atomicAdd(&agg[4 * 4096 + abase + (i * 2) * 128 + k], cap[k]);
  } else if (s == 7) {
    #pragma unroll
    for (int k = 0; k < 4; ++k) atomicAdd(&agg[4 * 4096 + abase + (i * 2 + 1) * 128 + k], cap[k]);
  }
  __shared__ f32x4 ls[8][32];
  ls[s][cg] = sum;
  __syncthreads();
  if (tid < 64) {
    const int h = tid >> 5, g = tid & 31;
    f32x4 T = ls[h * 4 + 0][g] + ls[h * 4 + 1][g] + ls[h * 4 + 2][g] + ls[h * 4 + 3][g];
    const int a = b * 512 + (i * 2 + h) * 128 + g * 4;
    #pragma unroll
    for (int k = 0; k < 4; ++k) atomicAdd(&agg[a + k], T[k]);
    if (rw == 0) {
      #pragma unroll
      for (int k = 0; k < 4; ++k) atomicAdd(&agg[4096 + a + k], T[k]);
    }
    if (rw == 63) {
      #pragma unroll
      for (int k = 0; k < 4; ++k) atomicAdd(&agg[2 * 4096 + a + k], T[k]);
    }
  }
}

// kprep: merged kR + kT + kF (block-specialized) — saves two launches.
//  bid <  18: R[w,c,t] = sum_o dc_w[w,o] * conv1_w[w*128+o, c, t]
//  bid < 274: gkT[w][j][c] = gk_w[c][w][j]
//  bid ==274: fsum[o] = sum_oc fusion_w[o, 512+oc]
__global__ void kprep(const float* __restrict__ dc_w, const float* __restrict__ conv1_w,
                      const float* __restrict__ gk_w, const float* __restrict__ fusion_w,
                      float* __restrict__ R, float* __restrict__ gkT,
                      float* __restrict__ fsum) {
  const int bid = blockIdx.x, tid = threadIdx.x;
  if (bid < 18) {
    int gid = bid * 256 + tid;                  // 0..4607
    int w = gid / 1152, m = gid % 1152;
    float s = 0.f;
    for (int o = 0; o < 128; ++o)
      s += dc_w[w * 128 + o] * conv1_w[(size_t)(w * 128 + o) * 1152 + m];
    R[gid] = s;
  } else if (bid < 274) {
    int gid = (bid - 18) * 256 + tid;           // 0..65535
    int w = gid >> 14, j = (gid >> 7) & 127, c = gid & 127;
    gkT[gid] = gk_w[c * 512 + w * 128 + j];
  } else if (tid < 128) {
    float s = 0.f;
    for (int oc = 0; oc < 128; ++oc) s += fusion_w[tid * 640 + 512 + oc];
    fsum[tid] = s;
  }
}

// K2: per-batch SE gate ww[b][w] from aggregates (S trick) + exact-gelu MLP + sigmoid
__global__ void k2_ww(const float* __restrict__ x, const float* __restrict__ agg,
                      const float* __restrict__ R, const float* __restrict__ dc_b,
                      const float* __restrict__ l1_w, const float* __restrict__ l1_b,
                      const float* __restrict__ l2_w, const float* __restrict__ l2_b,
                      float* __restrict__ ww) {
  const int b = blockIdx.x;
  const int tid = threadIdx.x;
  const int w = tid >> 6, lane = tid & 63;
  __shared__ float red[4];
  float partial = 0.f;
  const int i = w >> 1, j = w & 1;
  const int r0 = i * 64, s0 = j * 64;
  const size_t base = (size_t)b * 16384 * 128;
  #pragma unroll
  for (int k = 0; k < 2; ++k) {
    const int c = lane * 2 + k;
    const int ai = b * 512 + w * 128 + c;
    float T  = agg[ai];
    float rF = agg[4096 + ai];
    float rL = agg[2 * 4096 + ai];
    float cF = agg[3 * 4096 + ai];
    float cL = agg[4 * 4096 + ai];
    float c00 = x[base + ((size_t)(r0 + 0)  * 128 + (s0 + 0))  * 128 + c];
    float c0L = x[base + ((size_t)(r0 + 0)  * 128 + (s0 + 63)) * 128 + c];
    float cL0 = x[base + ((size_t)(r0 + 63) * 128 + (s0 + 0))  * 128 + c];
    float cLL = x[base + ((size_t)(r0 + 63) * 128 + (s0 + 63)) * 128 + c];
    float S[9];
    S[0] = T - rL - cL + cLL;
    S[1] = T - rL;
    S[2] = T - rL - cF + cL0;
    S[3] = T - cL;
    S[4] = T;
    S[5] = T - cF;
    S[6] = T - rF - cL + c0L;
    S[7] = T - rF;
    S[8] = T - rF - cF + c00;
    const float* Rp = R + (w * 128 + c) * 9;
    #pragma unroll
    for (int t = 0; t < 9; ++t) partial += S[t] * Rp[t];
  }
  for (int off = 32; off > 0; off >>= 1) partial += __shfl_xor(partial, off, 64);
  if (lane == 0) red[w] = partial;
  __syncthreads();
  if (tid == 0) {
    float ww0[4];
    #pragma unroll
    for (int w2 = 0; w2 < 4; ++w2) ww0[w2] = red[w2] * (1.f / 4096.f) + dc_b[w2];
    float h1[16];
    for (int i2 = 0; i2 < 16; ++i2) {
      float s = l1_b[i2];
      #pragma unroll
      for (int w2 = 0; w2 < 4; ++w2) s += l1_w[i2 * 4 + w2] * ww0[w2];
      h1[i2] = 0.5f * s * (1.f + erff(s * 0.70710678118654752f));
    }
    for (int w2 = 0; w2 < 4; ++w2) {
      float s = l2_b[w2];
      for (int i2 = 0; i2 < 16; ++i2) s += l2_w[w2 * 16 + i2] * h1[i2];
      ww[b * 4 + w2] = 1.f / (1.f + expf(-s));
    }
  }
}

// K3: A[w,o,m] = sum_oc fusion_w[o, w*128+oc]*cw[w,oc,m]; P same with fusion_w[o,512+oc]
//     m = c*9+t in [0,1152). Thread computes a float4 of m for one (w,o).
__global__ void k3_AP(const float* __restrict__ fusion_w, const float* __restrict__ conv1_w,
                      float* __restrict__ A, float* __restrict__ P) {
  int gid = blockIdx.x * 256 + threadIdx.x;   // 0..147455
  int w = gid / 36864;
  int rem = gid % 36864;
  int o = rem / 288;
  int m = (rem % 288) * 4;
  const float* fw1 = fusion_w + o * 640 + w * 128;
  const float* fw4 = fusion_w + o * 640 + 512;
  const float* cw = conv1_w + (size_t)w * 128 * 1152 + m;
  float a0 = 0, a1 = 0, a2 = 0, a3 = 0, p0 = 0, p1 = 0, p2 = 0, p3 = 0;
  for (int oc = 0; oc < 128; ++oc) {
    float f1 = fw1[oc], f4 = fw4[oc];
    float4 cv = *(const float4*)(cw + (size_t)oc * 1152);
    a0 += f1 * cv.x; a1 += f1 * cv.y; a2 += f1 * cv.z; a3 += f1 * cv.w;
    p0 += f4 * cv.x; p1 += f4 * cv.y; p2 += f4 * cv.z; p3 += f4 * cv.w;
  }
  float4* Ao = (float4*)(A + (size_t)(w * 128 + o) * 1152 + m);
  float4* Po = (float4*)(P + (size_t)(w * 128 + o) * 1152 + m);
  *Ao = make_float4(a0, a1, a2, a3);
  *Po = make_float4(p0, p1, p2, p3);
}

// K45: fused k4+k5 — eliminates the M round-trip (9.4 MB write + 18.9 MB read) and a launch.
// Block = (t, o-pair): keff[b,t,o,c] = f2bf( sum_w ww[b,w]*(A[w,o,c*9+t]
//                      + sum_j P[w,o,j*9+t]*gkT[w,j,c]) + fsum[o]*gk_b[c] )
// P/A slices staged in LDS (inner-loop reads are same-address broadcasts);
// gkT reads are lane-coalesced 256B rows; j split across two thread-halves, LDS-reduced.
__global__ void k45_keff(const float* __restrict__ A, const float* __restrict__ P,
                         const float* __restrict__ gkT, const float* __restrict__ ww,
                         const float* __restrict__ fsum, const float* __restrict__ gk_b,
                         u16* __restrict__ keff) {
  const int t = blockIdx.x >> 6;          // 0..8
  const int o0 = (blockIdx.x & 63) * 2;   // o-pair base
  const int tid = threadIdx.x;
  __shared__ float pl[2][4][128];
  __shared__ float al[2][4][128];
  __shared__ float red[2][2][4][128];
  #pragma unroll
  for (int rr = 0; rr < 4; ++rr) {
    const int idx = rr * 256 + tid;       // oi*512 + w*128 + j
    const int oi = idx >> 9, w = (idx >> 7) & 3, j = idx & 127;
    const size_t src = (size_t)(w * 128 + o0 + oi) * 1152 + j * 9 + t;
    pl[oi][w][j] = P[src];
    al[oi][w][j] = A[src];
  }
  __syncthreads();
  const int c = tid & 127, jh = tid >> 7;
  float acc[2][4];
  #pragma unroll
  for (int oi = 0; oi < 2; ++oi)
    #pragma unroll
    for (int w = 0; w < 4; ++w) acc[oi][w] = 0.f;
  const float* g = gkT + c;
  #pragma unroll 4
  for (int j = jh * 64; j < jh * 64 + 64; ++j) {
    const float g0 = g[0 * 16384 + j * 128];
    const float g1 = g[1 * 16384 + j * 128];
    const float g2 = g[2 * 16384 + j * 128];
    const float g3 = g[3 * 16384 + j * 128];
    #pragma unroll
    for (int oi = 0; oi < 2; ++oi) {
      acc[oi][0] += pl[oi][0][j] * g0;
      acc[oi][1] += pl[oi][1][j] * g1;
      acc[oi][2] += pl[oi][2][j] * g2;
      acc[oi][3] += pl[oi][3][j] * g3;
    }
  }
  #pragma unroll
  for (int oi = 0; oi < 2; ++oi)
    #pragma unroll
    for (int w = 0; w < 4; ++w) red[jh][oi][w][c] = acc[oi][w];
  __syncthreads();
  const int oi2 = tid >> 7, c2 = tid & 127;
  float m[4];
  #pragma unroll
  for (int w = 0; w < 4; ++w)
    m[w] = red[0][oi2][w][c2] + red[1][oi2][w][c2] + al[oi2][w][c2];
  const float base = fsum[o0 + oi2] * gk_b[c2];
  #pragma unroll
  for (int b = 0; b < 8; ++b) {
    float r = base;
    #pragma unroll
    for (int w = 0; w < 4; ++w) r += ww[b * 4 + w] * m[w];
    keff[(size_t)b * 147456 + (size_t)t * 16384 + (o0 + oi2) * 128 + c2] = f2bf(r);
  }
}

// K6: per-batch 3x3 C->C conv as 9 accumulated bf16 MFMA GEMMs.
// Block = (b, image row p): out tile 128 pixels x 128 o; 4 waves in 2x2 (64m x 64n each).
// BOTH operands staged in LDS.
//  - A: one padded image row staged once per dh-group via global_load_lds DMA with
//       PRE-SWIZZLED GLOBAL addresses (LDS dest linear).
//  - W: 32 KB/tap, single-buffered, reg-staged (loads overlap compute, write after barrier).
// Reads of both use off = lin ^ ((row&7)<<3). LDS total 66,560 B -> 2 blocks/CU.
__global__ __launch_bounds__(256, 2) void k6_conv(
    const u16* __restrict__ xpad, const u16* __restrict__ keff,
    const float* __restrict__ fusion_b, float* __restrict__ out) {
  __shared__ __align__(16) u16 alds[130 * 128];   // 33,280 B
  __shared__ __align__(16) u16 apad[256];         // 512 B guard for masked DMA tail
  __shared__ __align__(16) u16 wlds[128 * 128];   // 32,768 B
  const int tid = threadIdx.x;
  const int blk = blockIdx.x;
  const int b = blk & 7;            // XCD affinity: batch <-> XCD
  const int p = blk >> 3;
  const int wid = tid >> 6;
  const int lane = tid & 63;
  const int wm = (wid & 1) * 64;
  const int wn = (wid >> 1) * 64;
  const int quad = lane >> 4;
  const int l16 = lane & 15;

  f32x4 acc[4][4];
  #pragma unroll
  for (int i = 0; i < 4; ++i)
    #pragma unroll
    for (int j = 0; j < 4; ++j)
      acc[i][j] = (f32x4){0.f, 0.f, 0.f, 0.f};

  const u16* kb = keff + (size_t)b * 147456;
  const u16* xb = xpad + (size_t)b * 130 * 16640;
  bf16x8 streg[8];
  (void)apad;

  auto stage_W_load = [&](int tap) {
    const u16* src = kb + tap * 16384;
    #pragma unroll
    for (int it = 0; it < 8; ++it) {
      const int chunk = it * 256 + tid;
      const int gs = chunk ^ ((chunk >> 4) & 7);
      streg[it] = *(const bf16x8*)(src + gs * 8);
    }
  };
  auto stage_W_write = [&]() {
    #pragma unroll
    for (int it = 0; it < 8; ++it)
      *(bf16x8*)(wlds + (it * 256 + tid) * 8) = streg[it];
  };
  auto stage_A_dma = [&](int prow) {
    const u16* src = xb + (size_t)prow * 16640;
    #pragma unroll
    for (int r = 0; r < 8; ++r) {
      const int chunk = (wid * 8 + r) * 64 + lane;
      const int gs = chunk ^ ((chunk >> 4) & 7);
      __builtin_amdgcn_global_load_lds(
          (const __attribute__((address_space(1))) unsigned int*)(src + (size_t)gs * 8),
          (__attribute__((address_space(3))) unsigned int*)(alds + (wid * 8 + r) * 512),
          16, 0, 0);
    }
    if (tid < 32) {
      const int chunk = 2048 + tid;
      const int gs = chunk ^ ((chunk >> 4) & 7);
      __builtin_amdgcn_global_load_lds(
          (const __attribute__((address_space(1))) unsigned int*)(src + (size_t)gs * 8),
          (__attribute__((address_space(3))) unsigned int*)(alds + 2048 * 8),
          16, 0, 0);
    }
  };

  stage_W_load(0);
  stage_A_dma(p);
  stage_W_write();
  __syncthreads();   // drains vmcnt -> DMA complete, W visible

  for (int tap = 0; tap < 9; ++tap) {
    if (tap < 8) stage_W_load(tap + 1);         // global->reg, overlaps MFMA
    const int dw = tap % 3 - 1;
    const int pixoff = 1 + dw;
    #pragma unroll
    for (int kc = 0; kc < 4; ++kc) {
      const int c0 = kc * 32 + quad * 8;
      bf16x8 a[4], bb[4];
      #pragma unroll
      for (int i = 0; i < 4; ++i) {
        const int pix = pixoff + wm + i * 16 + l16;
        const int off = (pix * 128 + c0) ^ ((pix & 7) << 3);
        a[i] = *(const bf16x8*)(alds + off);
      }
      #pragma unroll
      for (int j = 0; j < 4; ++j) {
        const int row = wn + j * 16 + l16;
        const int off = (row * 128 + c0) ^ ((row & 7) << 3);
        bb[j] = *(const bf16x8*)(wlds + off);
      }
      #pragma unroll
      for (int i = 0; i < 4; ++i)
        #pragma unroll
        for (int j = 0; j < 4; ++j)
          acc[i][j] = __builtin_amdgcn_mfma_f32_16x16x32_bf16(a[i], bb[j], acc[i][j], 0, 0, 0);
    }
    __syncthreads();                            // all waves done reading alds/wlds
    if (tap < 8) {
      stage_W_write();                          // vmcnt waits streg, then ds_write
      if (tap % 3 == 2) stage_A_dma(p + (tap + 1) / 3);  // next dh row
      __syncthreads();                          // drains vmcnt -> DMA + writes visible
    }
  }

  float fb[4];
  #pragma unroll
  for (int j = 0; j < 4; ++j) fb[j] = fusion_b[wn + j * 16 + l16];
  float* outb = out + ((size_t)b * 16384 + (size_t)p * 128) * 128;
  #pragma unroll
  for (int i = 0; i < 4; ++i)
    #pragma unroll
    for (int r = 0; r < 4; ++r) {
      const int m = wm + i * 16 + quad * 4 + r;
      #pragma unroll
      for (int j = 0; j < 4; ++j)
        outb[(size_t)m * 128 + (wn + j * 16 + l16)] = acc[i][j][r] + fb[j];
    }
}

extern "C" void kernel_launch(void* const* d_in, const int* in_sizes, int n_in,
                              void* d_out, int out_size, void* d_ws, size_t ws_size,
                              hipStream_t stream) {
  const float* x        = (const float*)d_in[0];
  const float* conv1_w  = (const float*)d_in[1];
  const float* dc_w     = (const float*)d_in[2];
  const float* dc_b     = (const float*)d_in[3];
  const float* l1_w     = (const float*)d_in[4];
  const float* l1_b     = (const float*)d_in[5];
  const float* l2_w     = (const float*)d_in[6];
  const float* l2_b     = (const float*)d_in[7];
  const float* gk_w     = (const float*)d_in[8];
  const float* gk_b     = (const float*)d_in[9];
  const float* fusion_w = (const float*)d_in[10];
  const float* fusion_b = (const float*)d_in[11];
  float* out = (float*)d_out;
  char* ws = (char*)d_ws;

  float* agg  = (float*)(ws + OFF_AGG);
  float* ww   = (float*)(ws + OFF_WW);
  float* R    = (float*)(ws + OFF_R);
  float* fsum = (float*)(ws + OFF_FSUM);
  float* gkT  = (float*)(ws + OFF_GKT);
  float* A    = (float*)(ws + OFF_A);
  float* P    = (float*)(ws + OFF_P);
  u16* keff   = (u16*)(ws + OFF_KEFF);
  u16* xpad   = (u16*)(ws + OFF_XPAD);

  hipMemsetAsync(agg, 0, 81920, stream);
  k1_pad_agg<<<dim3(130, 8), 256, 0, stream>>>(x, xpad, agg);
  kprep<<<275, 256, 0, stream>>>(dc_w, conv1_w, gk_w, fusion_w, R, gkT, fsum);
  k2_ww<<<8, 256, 0, stream>>>(x, agg, R, dc_b, l1_w, l1_b, l2_w, l2_b, ww);
  k3_AP<<<576, 256, 0, stream>>>(fusion_w, conv1_w, A, P);
  k45_keff<<<576, 256, 0, stream>>>(A, P, gkT, ww, fsum, gk_b, keff);
  k6_conv<<<1024, 256, 0, stream>>>(xpad, keff, fusion_b, out);
}